// Round 8
// baseline (223.635 us; speedup 1.0000x reference)
//
#include <hip/hip_runtime.h>
#include <math.h>

#define T_SEQ 2048
#define NH    12
#define NB    2
#define BHC   (NB*NH)        // 24
#define NQT   32             // 2048/64

typedef _Float16 half4_t __attribute__((ext_vector_type(4)));
typedef _Float16 half8_t __attribute__((ext_vector_type(8)));
typedef float    floatx4 __attribute__((ext_vector_type(4)));

__device__ __forceinline__ half8_t h8splat(_Float16 s) {
  return (half8_t){s, s, s, s, s, s, s, s};
}

// ---------------- prep: f16 frag-order Q_aug/K_aug/V + premultiplied bias ----------------
// QF/KF chunk (tile16, dp, lane): row = tile16*16 + ln, d = dp*32 + quad*8 + j  (x32 frag order)
// VF chunk (tile64, v2, nt, lane): d = nt*16 + ln, key = tile64*64 + v2*32 + quad*4 + {j,16+j} (x16)
__global__ __launch_bounds__(256) void prep_kernel(
    const float* __restrict__ Q, const float* __restrict__ K,
    const float* __restrict__ V, const float* __restrict__ W,
    const float* __restrict__ wstd, const float* __restrict__ wrec,
    const float* __restrict__ dbias, const float* __restrict__ wdisc,
    ushort* __restrict__ QF, ushort* __restrict__ KF, ushort* __restrict__ VF,
    float* __restrict__ B2)
{
  __shared__ __align__(16) _Float16 Qsh[64*72];   // 144B row stride
  __shared__ __align__(16) _Float16 Ksh[64*72];
  __shared__ __align__(16) _Float16 Vsh[64*72];
  __shared__ __align__(16) _Float16 Lqh[64*16];
  __shared__ __align__(16) _Float16 Lkh[64*16];

  const int tid = threadIdx.x;
  const int w = tid >> 6, lane = tid & 63;
  const int quad = lane >> 4, ln = lane & 15;
  const int bh = blockIdx.x >> 5, tblk = blockIdx.x & 31;
  const long g0 = ((long)bh * T_SEQ + tblk * 64) * 64;

  const float4* gQ = (const float4*)(Q + g0);
  const float4* gK = (const float4*)(K + g0);
  const float4* gV = (const float4*)(V + g0);
  for (int i = tid; i < 1024; i += 256) {
    int r = i >> 4, c4 = i & 15;
    float4 q = gQ[i], k = gK[i], v = gV[i];
    *(half4_t*)&Qsh[r*72 + c4*4] = (half4_t){(_Float16)q.x,(_Float16)q.y,(_Float16)q.z,(_Float16)q.w};
    *(half4_t*)&Ksh[r*72 + c4*4] = (half4_t){(_Float16)k.x,(_Float16)k.y,(_Float16)k.z,(_Float16)k.w};
    *(half4_t*)&Vsh[r*72 + c4*4] = (half4_t){(_Float16)v.x,(_Float16)v.y,(_Float16)v.z,(_Float16)v.w};
  }
  __syncthreads();

  half4_t bw[4];
#pragma unroll
  for (int dk = 0; dk < 4; dk++)
#pragma unroll
    for (int i = 0; i < 4; i++)
      bw[dk][i] = (_Float16)W[(dk*16 + quad*4 + i)*16 + ln];

  floatx4 cq = {0.f,0.f,0.f,0.f}, ck = {0.f,0.f,0.f,0.f};
#pragma unroll
  for (int dk = 0; dk < 4; dk++) {
    half4_t aq = *(const half4_t*)&Qsh[(w*16 + ln)*72 + dk*16 + quad*4];
    half4_t ak = *(const half4_t*)&Ksh[(w*16 + ln)*72 + dk*16 + quad*4];
    cq = __builtin_amdgcn_mfma_f32_16x16x16f16(aq, bw[dk], cq, 0, 0, 0);
    ck = __builtin_amdgcn_mfma_f32_16x16x16f16(ak, bw[dk], ck, 0, 0, 0);
  }
#pragma unroll
  for (int i = 0; i < 4; i++) {            // C: row = 16w+quad*4+i, col = ln
    Lqh[(w*16 + quad*4 + i)*16 + ln] = (_Float16)cq[i];
    Lkh[(w*16 + quad*4 + i)*16 + ln] = (_Float16)ck[i];
  }
  __syncthreads();

  const int h = bh % NH;
  const float sstd = sqrtf(wstd[h]);
  const float srec = sqrtf(wrec[h]);
  const half8_t hq_std = h8splat((_Float16)(0.125f * sstd));  // 1/sqrt(64) folded
  const half8_t hk_std = h8splat((_Float16)sstd);
  const half8_t hq_rec = h8splat((_Float16)(0.125f * srec));
  const half8_t hk_rec = h8splat((_Float16)srec);

  // premultiplied bias
  if (tid < 64) B2[(long)bh*T_SEQ + tblk*64 + tid] =
      wdisc[h] * dbias[(long)bh*T_SEQ + tblk*64 + tid];

#pragma unroll
  for (int cc = 0; cc < 2; cc++) {
    int c = tid + cc * 256;                // chunk 0..511
    {
      int lp = c & 63, dp = (c >> 6) & 1, rt = c >> 7;
      int row = rt*16 + (lp & 15);
      int d0 = dp*32 + (lp >> 4)*8;        // 48-boundary on chunk boundary
      half8_t hq, hk;
      if (d0 < 48) {
        hq = *(const half8_t*)&Qsh[row*72 + d0] * hq_std;
        hk = *(const half8_t*)&Ksh[row*72 + d0] * hk_std;
      } else {
        hq = *(const half8_t*)&Lkh[row*16 + (d0-48)] * hq_rec;  // Q_aug gets K_low
        hk = *(const half8_t*)&Lqh[row*16 + (d0-48)] * hk_rec;  // K_aug gets Q_low
      }
      long tile16 = (long)bh*128 + tblk*4 + rt;
      ((int4*)QF)[tile16*128 + dp*64 + lp] = *(int4*)&hq;
      ((int4*)KF)[tile16*128 + dp*64 + lp] = *(int4*)&hk;
    }
    {
      int lv = c & 63, nt = (c >> 6) & 3, v2 = c >> 8;
      int d = nt*16 + (lv & 15), qv = lv >> 4;
      half8_t hv;
#pragma unroll
      for (int j = 0; j < 4; j++) {
        hv[j]   = Vsh[(v2*32 + qv*4 + j)*72 + d];
        hv[4+j] = Vsh[(v2*32 + 16 + qv*4 + j)*72 + d];
      }
      ((int4*)VF)[((long)bh*32 + tblk)*512 + (v2*4 + nt)*64 + lv] = *(int4*)&hv;
    }
  }
}

// ---------------- flash: one wave per PAIR of 16-row q-tiles, direct-L2, no LDS ----------------
// Tiles (2u, 2u+1) share ktmax = u>>1 exactly, so all K/V fragment loads amortize 2x,
// and the two softmax/MFMA chains are independent -> dual ILP hides L2 latency.
__global__ __launch_bounds__(64) void flash_kernel(
    const ushort* __restrict__ QF, const ushort* __restrict__ KF,
    const ushort* __restrict__ VF, const float* __restrict__ B2,
    float* __restrict__ Out)
{
  const int lane = threadIdx.x;
  const int quad = lane >> 4, ln = lane & 15;
  const int bid = blockIdx.x;
  const int bh  = bid % BHC;               // same bh -> same XCD (24 % 8 == 0)
  const int u   = 63 - bid / BHC;          // heavy pairs first
  const int qrow_a = 32*u + ln;            // tile a = 2u,   rows 32u..32u+15
  const int qrow_b = qrow_a + 16;          // tile b = 2u+1, rows 32u+16..+31
  const int ktmax = u >> 1;                // identical for both tiles

  const ushort* gK = KF + (long)bh * 131072;   // halves
  const ushort* gV = VF + (long)bh * 131072;
  const float*  gB = B2 + (long)bh * T_SEQ;

  // Q B-frags for both tiles (x32 layout), held in regs for the whole K-loop
  half8_t bqa[2], bqb[2];
  {
    const ushort* gQa = QF + ((long)bh*128 + 2*u) * 1024;
    bqa[0] = *(const half8_t*)(gQa + lane*8);
    bqa[1] = *(const half8_t*)(gQa + 512 + lane*8);
    bqb[0] = *(const half8_t*)(gQa + 1024 + lane*8);
    bqb[1] = *(const half8_t*)(gQa + 1536 + lane*8);
  }

  float m_a = -1e30f, l_a = 0.f, m_b = -1e30f, l_b = 0.f;
  floatx4 acca[4], accb[4];
#pragma unroll
  for (int nt = 0; nt < 4; nt++) {
    acca[nt] = (floatx4){0.f,0.f,0.f,0.f};
    accb[nt] = (floatx4){0.f,0.f,0.f,0.f};
  }

  for (int kt = 0; kt <= ktmax; kt++) {
    const ushort* Kt = gK + (long)kt * 4096;   // tile kt, frag order
    const ushort* Vt = gV + (long)kt * 4096;

    // ---- S^T for both tiles: st*[mt][i] = S[q=ln][key=kt*64+mt*16+quad*4+i]
    floatx4 sta[4], stb[4];
#pragma unroll
    for (int mt = 0; mt < 4; mt++) {
      half8_t a0 = *(const half8_t*)(Kt + (mt*2    )*512 + lane*8);
      half8_t a1 = *(const half8_t*)(Kt + (mt*2 + 1)*512 + lane*8);
      floatx4 ca = (floatx4){0.f,0.f,0.f,0.f};
      floatx4 cb = (floatx4){0.f,0.f,0.f,0.f};
      ca = __builtin_amdgcn_mfma_f32_16x16x32_f16(a0, bqa[0], ca, 0, 0, 0);
      cb = __builtin_amdgcn_mfma_f32_16x16x32_f16(a0, bqb[0], cb, 0, 0, 0);
      ca = __builtin_amdgcn_mfma_f32_16x16x32_f16(a1, bqa[1], ca, 0, 0, 0);
      cb = __builtin_amdgcn_mfma_f32_16x16x32_f16(a1, bqb[1], cb, 0, 0, 0);
      sta[mt] = ca; stb[mt] = cb;
    }

    // ---- bias + causal mask + online softmax (independent per tile) ----
    const bool diag = (kt == ktmax);
    float rma = -1e30f, rmb = -1e30f;
#pragma unroll
    for (int mt = 0; mt < 4; mt++) {
      float4 bb = *(const float4*)(gB + kt*64 + mt*16 + quad*4);
      float bv[4] = {bb.x, bb.y, bb.z, bb.w};
#pragma unroll
      for (int i = 0; i < 4; i++) {
        int key = kt*64 + mt*16 + quad*4 + i;
        float va = sta[mt][i] + bv[i];
        float vb = stb[mt][i] + bv[i];
        if (diag && key > qrow_a) va = -1e30f;
        if (diag && key > qrow_b) vb = -1e30f;
        sta[mt][i] = va; stb[mt][i] = vb;
        rma = fmaxf(rma, va); rmb = fmaxf(rmb, vb);
      }
    }
    rma = fmaxf(rma, __shfl_xor(rma, 16)); rma = fmaxf(rma, __shfl_xor(rma, 32));
    rmb = fmaxf(rmb, __shfl_xor(rmb, 16)); rmb = fmaxf(rmb, __shfl_xor(rmb, 32));
    float mna = fmaxf(m_a, rma), mnb = fmaxf(m_b, rmb);
    float ala = __expf(m_a - mna), alb = __expf(m_b - mnb);
    float psa = 0.f, psb = 0.f;
    half4_t paa[4], pab[4];             // C-regs are directly the x16 PV A-operand
#pragma unroll
    for (int mt = 0; mt < 4; mt++)
#pragma unroll
      for (int i = 0; i < 4; i++) {
        float pa = __expf(sta[mt][i] - mna);
        float pb = __expf(stb[mt][i] - mnb);
        psa += pa; psb += pb;
        paa[mt][i] = (_Float16)pa;
        pab[mt][i] = (_Float16)pb;
      }
    psa += __shfl_xor(psa, 16); psa += __shfl_xor(psa, 32);
    psb += __shfl_xor(psb, 16); psb += __shfl_xor(psb, 32);
    l_a = l_a * ala + psa;  m_a = mna;
    l_b = l_b * alb + psb;  m_b = mnb;

    float afa[4], afb[4];
#pragma unroll
    for (int i = 0; i < 4; i++) {
      afa[i] = __shfl(ala, quad*4 + i);
      afb[i] = __shfl(alb, quad*4 + i);
    }
#pragma unroll
    for (int nt = 0; nt < 4; nt++)
#pragma unroll
      for (int i = 0; i < 4; i++) {
        acca[nt][i] *= afa[i];
        accb[nt][i] *= afb[i];
      }

    // ---- O += P·V for both tiles (V frags amortized 2x) ----
#pragma unroll
    for (int v2 = 0; v2 < 2; v2++)
#pragma unroll
      for (int nt = 0; nt < 4; nt++) {
        half8_t vv = *(const half8_t*)(Vt + (v2*4 + nt)*512 + lane*8);
        half4_t b0 = __builtin_shufflevector(vv, vv, 0,1,2,3);
        half4_t b1 = __builtin_shufflevector(vv, vv, 4,5,6,7);
        acca[nt] = __builtin_amdgcn_mfma_f32_16x16x16f16(paa[2*v2],   b0, acca[nt], 0, 0, 0);
        accb[nt] = __builtin_amdgcn_mfma_f32_16x16x16f16(pab[2*v2],   b0, accb[nt], 0, 0, 0);
        acca[nt] = __builtin_amdgcn_mfma_f32_16x16x16f16(paa[2*v2+1], b1, acca[nt], 0, 0, 0);
        accb[nt] = __builtin_amdgcn_mfma_f32_16x16x16f16(pab[2*v2+1], b1, accb[nt], 0, 0, 0);
      }
  }

  // ---- epilogue (both tiles) ----
  float lra[4], lrb[4];
#pragma unroll
  for (int i = 0; i < 4; i++) {
    lra[i] = 1.f / __shfl(l_a, quad*4 + i);
    lrb[i] = 1.f / __shfl(l_b, quad*4 + i);
  }
  const long obase = (long)bh*T_SEQ*64 + (long)(32*u)*64;
#pragma unroll
  for (int i = 0; i < 4; i++)
#pragma unroll
    for (int nt = 0; nt < 4; nt++) {
      Out[obase + (quad*4 + i)*64        + nt*16 + ln] = acca[nt][i] * lra[i];
      Out[obase + (16 + quad*4 + i)*64   + nt*16 + ln] = accb[nt][i] * lrb[i];
    }
}

extern "C" void kernel_launch(void* const* d_in, const int* in_sizes, int n_in,
                              void* d_out, int out_size, void* d_ws, size_t ws_size,
                              hipStream_t stream) {
  const float* Q     = (const float*)d_in[0];
  const float* K     = (const float*)d_in[1];
  const float* V     = (const float*)d_in[2];
  const float* dbias = (const float*)d_in[3];
  const float* W     = (const float*)d_in[4];
  const float* wstd  = (const float*)d_in[5];
  const float* wrec  = (const float*)d_in[6];
  const float* wdisc = (const float*)d_in[7];
  float* Out = (float*)d_out;

  const long NEL = (long)BHC * T_SEQ * 64;
  ushort* QF = (ushort*)d_ws;            // f16 x32-frag-order Q_aug (scales folded)
  ushort* KF = QF + NEL;                 // f16 x32-frag-order K_aug
  ushort* VF = KF + NEL;                 // f16 x16-frag-order V
  float*  B2 = (float*)(VF + NEL);       // premultiplied wd*dbias

  prep_kernel<<<BHC * NQT, 256, 0, stream>>>(Q, K, V, W, wstd, wrec, dbias, wdisc,
                                             QF, KF, VF, B2);
  flash_kernel<<<BHC * 64, 64, 0, stream>>>(QF, KF, VF, B2, Out);
}

// Round 9
// 132.978 us; speedup vs baseline: 1.6817x; 1.6817x over previous
//
#include <hip/hip_runtime.h>
#include <math.h>

#define T_SEQ 2048
#define NH    12
#define NB    2
#define BHC   (NB*NH)        // 24
#define NQT   32             // 2048/64

typedef _Float16 half4_t __attribute__((ext_vector_type(4)));
typedef _Float16 half8_t __attribute__((ext_vector_type(8)));
typedef float    floatx4 __attribute__((ext_vector_type(4)));

__device__ __forceinline__ half8_t h8splat(_Float16 s) {
  return (half8_t){s, s, s, s, s, s, s, s};
}

// ---------------- prep: f16 frag-order Q_aug/K_aug/V + premultiplied bias ----------------
// QF/KF chunk (tile16, dp, lane): row = tile16*16 + ln, d = dp*32 + quad*8 + j  (x32 frag order)
// VF chunk (tile64, v2, nt, lane): d = nt*16 + ln, key = tile64*64 + v2*32 + quad*4 + {j,16+j} (x16)
__global__ __launch_bounds__(256) void prep_kernel(
    const float* __restrict__ Q, const float* __restrict__ K,
    const float* __restrict__ V, const float* __restrict__ W,
    const float* __restrict__ wstd, const float* __restrict__ wrec,
    const float* __restrict__ dbias, const float* __restrict__ wdisc,
    ushort* __restrict__ QF, ushort* __restrict__ KF, ushort* __restrict__ VF,
    float* __restrict__ B2)
{
  __shared__ __align__(16) _Float16 Qsh[64*72];   // 144B row stride
  __shared__ __align__(16) _Float16 Ksh[64*72];
  __shared__ __align__(16) _Float16 Vsh[64*72];
  __shared__ __align__(16) _Float16 Lqh[64*16];
  __shared__ __align__(16) _Float16 Lkh[64*16];

  const int tid = threadIdx.x;
  const int w = tid >> 6, lane = tid & 63;
  const int quad = lane >> 4, ln = lane & 15;
  const int bh = blockIdx.x >> 5, tblk = blockIdx.x & 31;
  const long g0 = ((long)bh * T_SEQ + tblk * 64) * 64;

  const float4* gQ = (const float4*)(Q + g0);
  const float4* gK = (const float4*)(K + g0);
  const float4* gV = (const float4*)(V + g0);
  for (int i = tid; i < 1024; i += 256) {
    int r = i >> 4, c4 = i & 15;
    float4 q = gQ[i], k = gK[i], v = gV[i];
    *(half4_t*)&Qsh[r*72 + c4*4] = (half4_t){(_Float16)q.x,(_Float16)q.y,(_Float16)q.z,(_Float16)q.w};
    *(half4_t*)&Ksh[r*72 + c4*4] = (half4_t){(_Float16)k.x,(_Float16)k.y,(_Float16)k.z,(_Float16)k.w};
    *(half4_t*)&Vsh[r*72 + c4*4] = (half4_t){(_Float16)v.x,(_Float16)v.y,(_Float16)v.z,(_Float16)v.w};
  }
  __syncthreads();

  half4_t bw[4];
#pragma unroll
  for (int dk = 0; dk < 4; dk++)
#pragma unroll
    for (int i = 0; i < 4; i++)
      bw[dk][i] = (_Float16)W[(dk*16 + quad*4 + i)*16 + ln];

  floatx4 cq = {0.f,0.f,0.f,0.f}, ck = {0.f,0.f,0.f,0.f};
#pragma unroll
  for (int dk = 0; dk < 4; dk++) {
    half4_t aq = *(const half4_t*)&Qsh[(w*16 + ln)*72 + dk*16 + quad*4];
    half4_t ak = *(const half4_t*)&Ksh[(w*16 + ln)*72 + dk*16 + quad*4];
    cq = __builtin_amdgcn_mfma_f32_16x16x16f16(aq, bw[dk], cq, 0, 0, 0);
    ck = __builtin_amdgcn_mfma_f32_16x16x16f16(ak, bw[dk], ck, 0, 0, 0);
  }
#pragma unroll
  for (int i = 0; i < 4; i++) {            // C: row = 16w+quad*4+i, col = ln
    Lqh[(w*16 + quad*4 + i)*16 + ln] = (_Float16)cq[i];
    Lkh[(w*16 + quad*4 + i)*16 + ln] = (_Float16)ck[i];
  }
  __syncthreads();

  const int h = bh % NH;
  const float sstd = sqrtf(wstd[h]);
  const float srec = sqrtf(wrec[h]);
  const half8_t hq_std = h8splat((_Float16)(0.125f * sstd));  // 1/sqrt(64) folded
  const half8_t hk_std = h8splat((_Float16)sstd);
  const half8_t hq_rec = h8splat((_Float16)(0.125f * srec));
  const half8_t hk_rec = h8splat((_Float16)srec);

  // premultiplied bias
  if (tid < 64) B2[(long)bh*T_SEQ + tblk*64 + tid] =
      wdisc[h] * dbias[(long)bh*T_SEQ + tblk*64 + tid];

#pragma unroll
  for (int cc = 0; cc < 2; cc++) {
    int c = tid + cc * 256;                // chunk 0..511
    {
      int lp = c & 63, dp = (c >> 6) & 1, rt = c >> 7;
      int row = rt*16 + (lp & 15);
      int d0 = dp*32 + (lp >> 4)*8;        // 48-boundary on chunk boundary
      half8_t hq, hk;
      if (d0 < 48) {
        hq = *(const half8_t*)&Qsh[row*72 + d0] * hq_std;
        hk = *(const half8_t*)&Ksh[row*72 + d0] * hk_std;
      } else {
        hq = *(const half8_t*)&Lkh[row*16 + (d0-48)] * hq_rec;  // Q_aug gets K_low
        hk = *(const half8_t*)&Lqh[row*16 + (d0-48)] * hk_rec;  // K_aug gets Q_low
      }
      long tile16 = (long)bh*128 + tblk*4 + rt;
      ((int4*)QF)[tile16*128 + dp*64 + lp] = *(int4*)&hq;
      ((int4*)KF)[tile16*128 + dp*64 + lp] = *(int4*)&hk;
    }
    {
      int lv = c & 63, nt = (c >> 6) & 3, v2 = c >> 8;
      int d = nt*16 + (lv & 15), qv = lv >> 4;
      half8_t hv;
#pragma unroll
      for (int j = 0; j < 4; j++) {
        hv[j]   = Vsh[(v2*32 + qv*4 + j)*72 + d];
        hv[4+j] = Vsh[(v2*32 + 16 + qv*4 + j)*72 + d];
      }
      ((int4*)VF)[((long)bh*32 + tblk)*512 + (v2*4 + nt)*64 + lv] = *(int4*)&hv;
    }
  }
}

// ---------------- flash: one wave per 16-row q-tile, direct-L2 reads,
// register-rotated cross-iteration prefetch (no LDS, no barriers) ----------------
__global__ __launch_bounds__(64, 3) void flash_kernel(
    const ushort* __restrict__ QF, const ushort* __restrict__ KF,
    const ushort* __restrict__ VF, const float* __restrict__ B2,
    float* __restrict__ Out)
{
  const int lane = threadIdx.x;
  const int quad = lane >> 4, ln = lane & 15;
  const int bid = blockIdx.x;
  const int bh  = bid % BHC;               // same bh -> same XCD (24 % 8 == 0)
  const int t16 = 127 - bid / BHC;         // heavy tiles first
  const int qrow = t16*16 + ln;            // this lane's q-row
  const int ktmax = t16 >> 2;              // last 64-key tile index

  const ushort* gK = KF + (long)bh * 131072;   // halves
  const ushort* gV = VF + (long)bh * 131072;
  const float*  gB = B2 + (long)bh * T_SEQ;

  // Q B-frags (x32 layout: d = quad*8+j per 32-slice), whole K-loop in regs
  half8_t bq[2];
  {
    const ushort* gQ = QF + ((long)bh*128 + t16) * 1024;
    bq[0] = *(const half8_t*)(gQ + lane*8);
    bq[1] = *(const half8_t*)(gQ + 512 + lane*8);
  }

  float m_i = -1e30f, l_i = 0.f;
  floatx4 acc[4];
#pragma unroll
  for (int nt = 0; nt < 4; nt++) acc[nt] = (floatx4){0.f,0.f,0.f,0.f};

  // prologue: tile 0 fragments into registers
  half8_t kf[8], vf[8];
#pragma unroll
  for (int c = 0; c < 8; c++) {
    kf[c] = *(const half8_t*)(gK + c*512 + lane*8);
    vf[c] = *(const half8_t*)(gV + c*512 + lane*8);
  }

  for (int kt = 0; kt <= ktmax; kt++) {
    // next-tile offset (last iter redundantly reloads current tile — L2 hit)
    const long onx = (long)(kt < ktmax ? kt + 1 : kt) * 4096;

    // ---- S^T = K_aug·Q_aug^T (x32): st[mt][i] = S[q=ln][key=kt*64+mt*16+quad*4+i]
    floatx4 st[4];
#pragma unroll
    for (int mt = 0; mt < 4; mt++) {
      floatx4 c = (floatx4){0.f,0.f,0.f,0.f};
      c = __builtin_amdgcn_mfma_f32_16x16x32_f16(kf[mt*2],     bq[0], c, 0, 0, 0);
      c = __builtin_amdgcn_mfma_f32_16x16x32_f16(kf[mt*2 + 1], bq[1], c, 0, 0, 0);
      st[mt] = c;
    }
    // kf dead -> rotate in next tile's K frags (landing hidden behind softmax+PV)
#pragma unroll
    for (int c = 0; c < 8; c++)
      kf[c] = *(const half8_t*)(gK + onx + c*512 + lane*8);

    // ---- bias + causal mask + online softmax (one q-row per lane) ----
    const bool diag = (kt == ktmax);
    float rowmax = -1e30f;
#pragma unroll
    for (int mt = 0; mt < 4; mt++) {
      float4 bb = *(const float4*)(gB + kt*64 + mt*16 + quad*4);  // quad-uniform
      float bv[4] = {bb.x, bb.y, bb.z, bb.w};
#pragma unroll
      for (int i = 0; i < 4; i++) {
        float v = st[mt][i] + bv[i];
        int key = kt*64 + mt*16 + quad*4 + i;
        if (diag && key > qrow) v = -1e30f;
        st[mt][i] = v;
        rowmax = fmaxf(rowmax, v);
      }
    }
    rowmax = fmaxf(rowmax, __shfl_xor(rowmax, 16));
    rowmax = fmaxf(rowmax, __shfl_xor(rowmax, 32));
    float mnew  = fmaxf(m_i, rowmax);
    float alpha = __expf(m_i - mnew);
    float psum = 0.f;
    half4_t pa[4];                        // C-regs are directly the x16 PV A-operand
#pragma unroll
    for (int mt = 0; mt < 4; mt++)
#pragma unroll
      for (int i = 0; i < 4; i++) {
        float p = __expf(st[mt][i] - mnew);
        psum += p;
        pa[mt][i] = (_Float16)p;
      }
    psum += __shfl_xor(psum, 16);
    psum += __shfl_xor(psum, 32);
    l_i = l_i * alpha + psum;
    m_i = mnew;

    float af[4];
#pragma unroll
    for (int i = 0; i < 4; i++) af[i] = __shfl(alpha, quad*4 + i);
#pragma unroll
    for (int nt = 0; nt < 4; nt++)
#pragma unroll
      for (int i = 0; i < 4; i++) acc[nt][i] *= af[i];

    // ---- O += P·V (x16; P stays in registers) ----
#pragma unroll
    for (int v2 = 0; v2 < 2; v2++)
#pragma unroll
      for (int nt = 0; nt < 4; nt++) {
        half8_t vv = vf[v2*4 + nt];
        half4_t b0 = __builtin_shufflevector(vv, vv, 0,1,2,3);
        half4_t b1 = __builtin_shufflevector(vv, vv, 4,5,6,7);
        acc[nt] = __builtin_amdgcn_mfma_f32_16x16x16f16(pa[2*v2],   b0, acc[nt], 0, 0, 0);
        acc[nt] = __builtin_amdgcn_mfma_f32_16x16x16f16(pa[2*v2+1], b1, acc[nt], 0, 0, 0);
      }
    // vf dead -> rotate in next tile's V frags (landing hidden behind next QK+softmax)
#pragma unroll
    for (int c = 0; c < 8; c++)
      vf[c] = *(const half8_t*)(gV + onx + c*512 + lane*8);
  }

  // ---- epilogue ----
  float lr[4];
#pragma unroll
  for (int i = 0; i < 4; i++) lr[i] = 1.f / __shfl(l_i, quad*4 + i);
  const long obase = (long)bh*T_SEQ*64 + (long)(t16*16)*64;
#pragma unroll
  for (int i = 0; i < 4; i++)
#pragma unroll
    for (int nt = 0; nt < 4; nt++)
      Out[obase + (quad*4 + i)*64 + nt*16 + ln] = acc[nt][i] * lr[i];
}

extern "C" void kernel_launch(void* const* d_in, const int* in_sizes, int n_in,
                              void* d_out, int out_size, void* d_ws, size_t ws_size,
                              hipStream_t stream) {
  const float* Q     = (const float*)d_in[0];
  const float* K     = (const float*)d_in[1];
  const float* V     = (const float*)d_in[2];
  const float* dbias = (const float*)d_in[3];
  const float* W     = (const float*)d_in[4];
  const float* wstd  = (const float*)d_in[5];
  const float* wrec  = (const float*)d_in[6];
  const float* wdisc = (const float*)d_in[7];
  float* Out = (float*)d_out;

  const long NEL = (long)BHC * T_SEQ * 64;
  ushort* QF = (ushort*)d_ws;            // f16 x32-frag-order Q_aug (scales folded)
  ushort* KF = QF + NEL;                 // f16 x32-frag-order K_aug
  ushort* VF = KF + NEL;                 // f16 x16-frag-order V
  float*  B2 = (float*)(VF + NEL);       // premultiplied wd*dbias

  prep_kernel<<<BHC * NQT, 256, 0, stream>>>(Q, K, V, W, wstd, wrec, dbias, wdisc,
                                             QF, KF, VF, B2);
  flash_kernel<<<BHC * 128, 64, 0, stream>>>(QF, KF, VF, B2, Out);
}